// Round 15
// baseline (566.308 us; speedup 1.0000x reference)
//
#include <hip/hip_runtime.h>

#define B_    32
#define N_    64
#define IN_   2048
#define D_    32
#define K_    16
#define CELLS  ((size_t)B_*N_*D_)      /* 65536 */
#define WELEMS ((size_t)N_*IN_*D_*K_)  /* 67108864 */
#define UH_ELEMS ((size_t)B_*IN_*N_*D_) /* 134217728 */
#define UH_BYTES (UH_ELEMS*2)          /* 256 MB */
#define TI_A   8                        /* i's per uhatC block */
#define NTILE_A (IN_/TI_A)              /* 256 */
#define T_B    16                       /* i's per routeB block */
#define NTILE_B (IN_/T_B)               /* 128 */
#define NBLK_B  (NTILE_B*8)             /* 1024 */

// softmax_e(v * INV_LOG2) == 2^((v-max) * (1/ln2)^2)
#define SM_SCALE 2.0813689810056077f

// ---- bf16 helpers (RNE) ----
__device__ __forceinline__ unsigned int rb(float f) {
    unsigned int u = __float_as_uint(f);
    return (u + 0x7fffu + ((u >> 16) & 1u)) >> 16;
}
__device__ __forceinline__ float blo(unsigned int u) { return __uint_as_float(u << 16); }
__device__ __forceinline__ float bhi(unsigned int u) { return __uint_as_float(u & 0xffff0000u); }

__device__ __forceinline__ float dot8(uint4 q, const float* o) {
    return blo(q.x)*o[0] + bhi(q.x)*o[1] + blo(q.y)*o[2] + bhi(q.y)*o[3]
         + blo(q.z)*o[4] + bhi(q.z)*o[5] + blo(q.w)*o[6] + bhi(q.w)*o[7];
}
__device__ __forceinline__ void acc8(float* s, uint4 q, float c) {
    s[0] += c*blo(q.x); s[1] += c*bhi(q.x); s[2] += c*blo(q.y); s[3] += c*bhi(q.y);
    s[4] += c*blo(q.z); s[5] += c*bhi(q.z); s[6] += c*blo(q.w); s[7] += c*bhi(q.w);
}

__global__ __launch_bounds__(256)
void zero_kernel(float4* __restrict__ os)
{
    os[blockIdx.x * 256 + threadIdx.x] = float4{0.f, 0.f, 0.f, 0.f};
}

// -----------------------------------------------------------------------------
// uhatC_kernel: u_hat[i][b][n][d] (bf16) FUSED with routing pass 0.
// Pass 0's c is uniform (1/64), so s0[b,n,d] = (1/64) sum_i uh accumulates
// during production -- saves the entire 256 MB pass-0 routeB read.
// R11's fused attempt died on s0[32] regs (VGPR 104, occ 23%); here the b-loop
// is CHUNKED (bc outer, s0[8] regs, flush per chunk), cost = W rows re-read
// 4x (bc>=1 from L2/L3). x staged in LDS (R14 win, +30% on uhat).
// Block=(i-tile of 8, n-chunk of 8); thread=(n,d). ~50 VGPR.
// -----------------------------------------------------------------------------
__global__ __launch_bounds__(256, 1)
void uhatC_kernel(const float* __restrict__ x, const float* __restrict__ W,
                  unsigned short* __restrict__ uhat, float* __restrict__ part)
{
    __shared__ float x_s[B_][TI_A][K_];   // 16 KB: x[b][ii][k]

    const int tid   = threadIdx.x;
    const int itile = blockIdx.x >> 3;
    const int chunk = blockIdx.x & 7;
    const int n     = chunk * 8 + (tid >> 5);
    const int d     = tid & 31;
    const int i0    = itile * TI_A;

    {   // stage x[:, i0..i0+7, :]: 4096 floats; per-b 512B contiguous
        #pragma unroll
        for (int v = 0; v < 4; ++v) {
            const int f = tid + v * 256;        // float4 index 0..1023
            const int b = f >> 5;               // 128 floats per b
            const int r = (f & 31) * 4;
            ((float4*)x_s)[f] = *(const float4*)(x + (size_t)b * (IN_ * K_)
                                                   + (size_t)i0 * K_ + r);
        }
    }
    __syncthreads();

    const float* wbase = W + (((size_t)n * IN_ + i0) * D_ + d) * K_;

    #pragma unroll 1
    for (int bc = 0; bc < 4; ++bc) {
        float s0[8];
        #pragma unroll
        for (int jb = 0; jb < 8; ++jb) s0[jb] = 0.f;

        #pragma unroll 1
        for (int ii = 0; ii < TI_A; ++ii) {
            const float4* wp = (const float4*)(wbase + (size_t)ii * (D_ * K_));
            const float4 w0 = wp[0], w1 = wp[1], w2 = wp[2], w3 = wp[3];
            unsigned short* up = uhat + (size_t)(i0 + ii) * (B_ * N_ * D_)
                                      + (size_t)(bc * 8) * (N_ * D_) + n * D_ + d;
            #pragma unroll
            for (int jb = 0; jb < 8; ++jb) {
                const int b = bc * 8 + jb;
                const float4 x0 = ((const float4*)&x_s[b][ii][0])[0];  // broadcast
                const float4 x1 = ((const float4*)&x_s[b][ii][0])[1];
                const float4 x2 = ((const float4*)&x_s[b][ii][0])[2];
                const float4 x3 = ((const float4*)&x_s[b][ii][0])[3];
                const float uh = w0.x*x0.x + w0.y*x0.y + w0.z*x0.z + w0.w*x0.w
                               + w1.x*x1.x + w1.y*x1.y + w1.z*x1.z + w1.w*x1.w
                               + w2.x*x2.x + w2.y*x2.y + w2.z*x2.z + w2.w*x2.w
                               + w3.x*x3.x + w3.y*x3.y + w3.z*x3.z + w3.w*x3.w;
                up[(size_t)jb * (N_ * D_)] = (unsigned short)rb(uh);
                s0[jb] += uh;
            }
        }
        // flush pass-0 partials: part[itile][(b*N+n)*D+d], c = 1/64
        float* myp = part + (size_t)itile * CELLS
                   + ((size_t)(bc * 8) * N_ + n) * D_ + d;
        #pragma unroll
        for (int jb = 0; jb < 8; ++jb)
            myp[(size_t)jb * (N_ * D_)] = s0[jb] * (1.0f / 64.0f);
    }
}

// -----------------------------------------------------------------------------
// routeB_kernel: one routing pass reading u_hat[i][b][n][d] (bf16, single
// touch, contiguous per (i,b)). Thread=(b-in-group, n): 256 thr = 4b x 64n;
// block=(i-tile of 16, b-group). logit = thread-local dot over d; softmax
// over n = one 64-lane butterfly; s_acc[32] in regs. R13/R14: ~58us/pass.
// -----------------------------------------------------------------------------
__global__ __launch_bounds__(256, 1)
void routeB_kernel(const unsigned short* __restrict__ uhat,
                   const float* __restrict__ os, float* __restrict__ part)
{
    const int tid  = threadIdx.x;
    const int jb   = tid >> 6;          // wave = batch-in-group
    const int n    = tid & 63;          // lane = n
    const int tile = blockIdx.x >> 3;
    const int bg   = blockIdx.x & 7;
    const int b    = bg * 4 + jb;
    const int i0   = tile * T_B;

    float s_acc[D_];
    #pragma unroll
    for (int d = 0; d < D_; ++d) s_acc[d] = 0.f;

    float osr[D_];
    {
        const float4* op = (const float4*)(os + ((size_t)b * N_ + n) * D_);
        #pragma unroll
        for (int d4 = 0; d4 < 8; ++d4) *(float4*)&osr[d4 * 4] = op[d4];
    }

    const unsigned short* up = uhat + ((size_t)i0 * B_ + b) * (N_ * D_) + n * D_;

    #pragma unroll 2
    for (int ii = 0; ii < T_B; ++ii) {
        const uint4 q0 = *(const uint4*)(up);
        const uint4 q1 = *(const uint4*)(up + 8);
        const uint4 q2 = *(const uint4*)(up + 16);
        const uint4 q3 = *(const uint4*)(up + 24);
        up += (size_t)B_ * N_ * D_;     // next i, same b

        float t = dot8(q0, osr) + dot8(q1, osr + 8)
                + dot8(q2, osr + 16) + dot8(q3, osr + 24);
        float mx = t;
        #pragma unroll
        for (int m = 1; m < 64; m <<= 1) mx = fmaxf(mx, __shfl_xor(mx, m, 64));
        const float e = exp2f((t - mx) * SM_SCALE);
        float sum = e;
        #pragma unroll
        for (int m = 1; m < 64; m <<= 1) sum += __shfl_xor(sum, m, 64);
        const float c = e / sum;
        acc8(s_acc, q0, c); acc8(s_acc + 8,  q1, c);
        acc8(s_acc + 16, q2, c); acc8(s_acc + 24, q3, c);
    }

    float4* myp = (float4*)(part + (size_t)tile * CELLS + ((size_t)b * N_ + n) * D_);
    #pragma unroll
    for (int d4 = 0; d4 < 8; ++d4) {
        float4 v;
        v.x = s_acc[d4*4 + 0]; v.y = s_acc[d4*4 + 1];
        v.z = s_acc[d4*4 + 2]; v.w = s_acc[d4*4 + 3];
        myp[d4] = v;
    }
}

// -----------------------------------------------------------------------------
// finishB_kernel: s = sum over ntiles tile-partials; out = squash(s);
// FINAL=false: os += out; FINAL=true: write d_out.
// -----------------------------------------------------------------------------
template<bool FINAL>
__global__ __launch_bounds__(256)
void finishB_kernel(const float* __restrict__ part, int ntiles,
                    float* __restrict__ os, float* __restrict__ out)
{
    const int gid = blockIdx.x * 256 + threadIdx.x;   // 0..65535 = b*2048+n*32+d
    float v = 0.f;
    for (int t = 0; t < ntiles; ++t) v += part[(size_t)t * CELLS + gid];
    float sq = v * v;
    #pragma unroll
    for (int m = 1; m < 32; m <<= 1) sq += __shfl_xor(sq, m, 64);  // sum over d
    const float scale = sqrtf(sq) / (1.0f + sq);
    const float o = v * scale;
    if (FINAL) out[gid] = o;
    else       os[gid] += o;
}

// =============================================================================
// ===== R8 fallback path -- used only if ws < ~320 MB =========================
// =============================================================================
#define BH    4
#define NBG   (B_/BH)
#define ITILE 8
#define NTILE (IN_/ITILE)
#define NBLK  (NTILE*NBG)
#define PCELLS ((size_t)BH*N_*D_)

__global__ __launch_bounds__(256)
void convert_kernel(const float4* __restrict__ W, uint4* __restrict__ W16)
{
    const size_t n8 = WELEMS / 8;
    const size_t stride = (size_t)gridDim.x * 256;
    for (size_t i = (size_t)blockIdx.x * 256 + threadIdx.x; i < n8; i += stride) {
        const float4 a = W[2 * i], b = W[2 * i + 1];
        uint4 o;
        o.x = rb(a.x) | (rb(a.y) << 16);
        o.y = rb(a.z) | (rb(a.w) << 16);
        o.z = rb(b.x) | (rb(b.y) << 16);
        o.w = rb(b.z) | (rb(b.w) << 16);
        W16[i] = o;
    }
}

template<bool FIRST>
__global__ __launch_bounds__(256, 1)
void route16_kernel(const float* __restrict__ x, const unsigned short* __restrict__ W16,
                    const float* __restrict__ os, float* __restrict__ part)
{
    __shared__ unsigned short uh_s[N_][D_][BH];
    __shared__ float logit_s[BH][N_];

    const int tid  = threadIdx.x;
    const int w    = tid >> 6;
    const int l    = tid & 63;
    const int d    = l & 31;
    const int hi   = l >> 5;
    const int slot = w * 2 + hi;

    const int virt = (blockIdx.x & 7) * (NBLK / 8) + (blockIdx.x >> 3);
    const int tile = virt / NBG;
    const int bg   = virt % NBG;
    const int b0   = bg * BH;
    const int i0   = tile * ITILE;

    float s_acc[8][BH];
    #pragma unroll
    for (int r = 0; r < 8; ++r)
        #pragma unroll
        for (int jb = 0; jb < BH; ++jb) s_acc[r][jb] = 0.f;

    const unsigned short* wb = W16 + (((size_t)slot * IN_ + i0) * D_ + d) * K_;

    for (int ii = 0; ii < ITILE; ++ii) {
        const float* xb = x + (size_t)b0 * (IN_ * K_) + (size_t)(i0 + ii) * K_;

        #pragma unroll
        for (int r = 0; r < 8; ++r) {
            const int n = r * 8 + slot;
            const unsigned short* wr = wb + (size_t)r * (8ull * IN_ * D_ * K_)
                                          + (size_t)ii * (D_ * K_);
            const uint4 plo = *(const uint4*)(wr);
            const uint4 phi = *(const uint4*)(wr + 8);
            float wf[16];
            wf[ 0]=blo(plo.x); wf[ 1]=bhi(plo.x); wf[ 2]=blo(plo.y); wf[ 3]=bhi(plo.y);
            wf[ 4]=blo(plo.z); wf[ 5]=bhi(plo.z); wf[ 6]=blo(plo.w); wf[ 7]=bhi(plo.w);
            wf[ 8]=blo(phi.x); wf[ 9]=bhi(phi.x); wf[10]=blo(phi.y); wf[11]=bhi(phi.y);
            wf[12]=blo(phi.z); wf[13]=bhi(phi.z); wf[14]=blo(phi.w); wf[15]=bhi(phi.w);

            float uh[BH];
            #pragma unroll
            for (int jb = 0; jb < BH; ++jb) {
                const float4 x0 = *(const float4*)(xb + (size_t)jb * (IN_ * K_) + 0);
                const float4 x1 = *(const float4*)(xb + (size_t)jb * (IN_ * K_) + 4);
                const float4 x2 = *(const float4*)(xb + (size_t)jb * (IN_ * K_) + 8);
                const float4 x3 = *(const float4*)(xb + (size_t)jb * (IN_ * K_) + 12);
                uh[jb] = wf[ 0]*x0.x + wf[ 1]*x0.y + wf[ 2]*x0.z + wf[ 3]*x0.w
                       + wf[ 4]*x1.x + wf[ 5]*x1.y + wf[ 6]*x1.z + wf[ 7]*x1.w
                       + wf[ 8]*x2.x + wf[ 9]*x2.y + wf[10]*x2.z + wf[11]*x2.w
                       + wf[12]*x3.x + wf[13]*x3.y + wf[14]*x3.z + wf[15]*x3.w;
            }

            if (FIRST) {
                #pragma unroll
                for (int jb = 0; jb < BH; ++jb) s_acc[r][jb] += uh[jb];
            } else {
                uint2 pk;
                pk.x = rb(uh[0]) | (rb(uh[1]) << 16);
                pk.y = rb(uh[2]) | (rb(uh[3]) << 16);
                *(uint2*)&uh_s[n][d][0] = pk;
                #pragma unroll
                for (int jb = 0; jb < BH; ++jb) {
                    float t = uh[jb] * os[((size_t)(b0 + jb) * N_ + n) * D_ + d];
                    #pragma unroll
                    for (int m = 1; m < 32; m <<= 1) t += __shfl_xor(t, m, 64);
                    if (d == 0) logit_s[jb][n] = t;
                }
            }
        }

        if (!FIRST) {
            __syncthreads();
            {
                const float v = logit_s[w][l];
                float mx = v;
                #pragma unroll
                for (int m = 1; m < 64; m <<= 1) mx = fmaxf(mx, __shfl_xor(mx, m, 64));
                const float e = exp2f((v - mx) * SM_SCALE);
                float sum = e;
                #pragma unroll
                for (int m = 1; m < 64; m <<= 1) sum += __shfl_xor(sum, m, 64);
                logit_s[w][l] = e / sum;
            }
            __syncthreads();
            #pragma unroll
            for (int r = 0; r < 8; ++r) {
                const int n = r * 8 + slot;
                const uint2 pk = *(const uint2*)&uh_s[n][d][0];
                s_acc[r][0] += logit_s[0][n] * blo(pk.x);
                s_acc[r][1] += logit_s[1][n] * bhi(pk.x);
                s_acc[r][2] += logit_s[2][n] * blo(pk.y);
                s_acc[r][3] += logit_s[3][n] * bhi(pk.y);
            }
            __syncthreads();
        }
    }

    const float scale = FIRST ? (1.0f / 64.0f) : 1.0f;
    float* myp = part + (size_t)virt * PCELLS;
    #pragma unroll
    for (int r = 0; r < 8; ++r) {
        const int n = r * 8 + slot;
        #pragma unroll
        for (int jb = 0; jb < BH; ++jb)
            myp[((size_t)jb * N_ + n) * D_ + d] = s_acc[r][jb] * scale;
    }
}

template<bool FINAL>
__global__ __launch_bounds__(256)
void finish_kernel(const float* __restrict__ part,
                   float* __restrict__ os, float* __restrict__ out)
{
    const int gid = blockIdx.x * 256 + threadIdx.x;
    const int b   = gid >> 11;
    const int rem = gid & 2047;
    const int bg = b >> 2, jb = b & 3;
    const float* p0 = part + (size_t)bg * PCELLS + (size_t)jb * (N_ * D_) + rem;
    float v = 0.f;
    for (int t = 0; t < NTILE; ++t) v += p0[(size_t)t * NBG * PCELLS];
    float sq = v * v;
    #pragma unroll
    for (int m = 1; m < 32; m <<= 1) sq += __shfl_xor(sq, m, 64);
    const float scale = sqrtf(sq) / (1.0f + sq);
    const float o = v * scale;
    if (FINAL) out[gid] = o;
    else       os[gid] += o;
}

extern "C" void kernel_launch(void* const* d_in, const int* in_sizes, int n_in,
                              void* d_out, int out_size, void* d_ws, size_t ws_size,
                              hipStream_t stream)
{
    const float* x = (const float*)d_in[0];
    const float* W = (const float*)d_in[1];
    float* out = (float*)d_out;

    const size_t partA_bytes = (size_t)NTILE_A * CELLS * 4;   // 64 MB (pass 0)
    const size_t need_new    = UH_BYTES + partA_bytes + CELLS * 4;

    if (ws_size >= need_new) {
        unsigned short* uhat = (unsigned short*)d_ws;
        float* part = (float*)((char*)d_ws + UH_BYTES);
        float* os   = part + (size_t)NTILE_A * CELLS;

        zero_kernel<<<CELLS / 1024, 256, 0, stream>>>((float4*)os);
        uhatC_kernel<<<NTILE_A * 8, 256, 0, stream>>>(x, W, uhat, part);   // + pass 0
        finishB_kernel<false><<<CELLS / 256, 256, 0, stream>>>(part, NTILE_A, os, nullptr);
        routeB_kernel<<<NBLK_B, 256, 0, stream>>>(uhat, os, part);          // pass 1
        finishB_kernel<false><<<CELLS / 256, 256, 0, stream>>>(part, NTILE_B, os, nullptr);
        routeB_kernel<<<NBLK_B, 256, 0, stream>>>(uhat, os, part);          // pass 2
        finishB_kernel<true ><<<CELLS / 256, 256, 0, stream>>>(part, NTILE_B, nullptr, out);
        return;
    }

    // ---- R8 fallback (proven) ----
    const size_t w16_bytes = WELEMS * 2;
    unsigned short* W16 = (unsigned short*)d_ws;
    float* part = (float*)((char*)d_ws + w16_bytes);
    float* os   = part + (size_t)NBLK * PCELLS;

    zero_kernel<<<CELLS / 1024, 256, 0, stream>>>((float4*)os);
    convert_kernel<<<2048, 256, 0, stream>>>((const float4*)W, (uint4*)d_ws);

    for (int it = 0; it < 3; ++it) {
        if (it == 0) route16_kernel<true ><<<NBLK, 256, 0, stream>>>(x, W16, os, part);
        else         route16_kernel<false><<<NBLK, 256, 0, stream>>>(x, W16, os, part);
        if (it < 2)  finish_kernel<false><<<CELLS / 256, 256, 0, stream>>>(part, os, nullptr);
        else         finish_kernel<true ><<<CELLS / 256, 256, 0, stream>>>(part, nullptr, out);
    }
}

// Round 16
// 477.837 us; speedup vs baseline: 1.1851x; 1.1851x over previous
//
#include <hip/hip_runtime.h>

#define B_    32
#define N_    64
#define IN_   2048
#define D_    32
#define K_    16
#define CELLS  ((size_t)B_*N_*D_)      /* 65536 */
#define WELEMS ((size_t)N_*IN_*D_*K_)  /* 67108864 */
#define UH_ELEMS ((size_t)B_*IN_*N_*D_) /* 134217728 */
#define UH_BYTES (UH_ELEMS*2)          /* 256 MB */
#define TI_A   8                        /* i's per uhatD block */
#define NTILE_A (IN_/TI_A)              /* 256 */
#define NBLK_A  (NTILE_A*8*4)           /* 8192: itile x chunk x bgroup */
#define T_B    16                       /* i's per routeB block */
#define NTILE_B (IN_/T_B)               /* 128 */
#define NBLK_B  (NTILE_B*8)             /* 1024 */

// softmax_e(v * INV_LOG2) == 2^((v-max) * (1/ln2)^2)
#define SM_SCALE 2.0813689810056077f

// ---- bf16 helpers (RNE) ----
__device__ __forceinline__ unsigned int rb(float f) {
    unsigned int u = __float_as_uint(f);
    return (u + 0x7fffu + ((u >> 16) & 1u)) >> 16;
}
__device__ __forceinline__ float blo(unsigned int u) { return __uint_as_float(u << 16); }
__device__ __forceinline__ float bhi(unsigned int u) { return __uint_as_float(u & 0xffff0000u); }

__device__ __forceinline__ float dot8(uint4 q, const float* o) {
    return blo(q.x)*o[0] + bhi(q.x)*o[1] + blo(q.y)*o[2] + bhi(q.y)*o[3]
         + blo(q.z)*o[4] + bhi(q.z)*o[5] + blo(q.w)*o[6] + bhi(q.w)*o[7];
}
__device__ __forceinline__ void acc8(float* s, uint4 q, float c) {
    s[0] += c*blo(q.x); s[1] += c*bhi(q.x); s[2] += c*blo(q.y); s[3] += c*bhi(q.y);
    s[4] += c*blo(q.z); s[5] += c*bhi(q.z); s[6] += c*blo(q.w); s[7] += c*bhi(q.w);
}

__global__ __launch_bounds__(256)
void zero_kernel(float4* __restrict__ os)
{
    os[blockIdx.x * 256 + threadIdx.x] = float4{0.f, 0.f, 0.f, 0.f};
}

// -----------------------------------------------------------------------------
// uhatD_kernel: u_hat[i][b][n][d] (bf16) fused with routing pass 0, attempt 3.
// R11 (s0[32] regs) died on VGPR/occupancy; R15 (in-block bc loop) died on
// temporal L2 reuse (FETCH 539MB: re-read distance too long, L2 churned).
// Here b is split ACROSS blocks (4 b-groups of 8 -> s0[8] regs), and the 4
// blocks sharing an (itile,chunk) W slice are virt-CONSECUTIVE on one XCD
// (R5 swizzle, where NBG=8 sharing kept FETCH at 1x|W|): W line fetched once
// into L2, hit 3x concurrently. W read once per block (no re-read loop).
// Block=(itile of 8 i, n-chunk of 8, b-group of 8); thread=(n,d). ~56 VGPR,
// LDS 4KB. Pass-0 partials: part[itile][(b*N+n)*D+d], c = 1/64.
// -----------------------------------------------------------------------------
__global__ __launch_bounds__(256, 1)
void uhatD_kernel(const float* __restrict__ x, const float* __restrict__ W,
                  unsigned short* __restrict__ uhat, float* __restrict__ part)
{
    __shared__ float x_s[8][TI_A][K_];   // 4 KB: x[jb][ii][k]

    const int tid = threadIdx.x;
    // XCD swizzle: virt-consecutive blocks live on the SAME XCD (bid%8 = XCD)
    const int virt  = (blockIdx.x & 7) * (NBLK_A / 8) + (blockIdx.x >> 3);
    const int bg    = virt & 3;          // b-group: 4 consecutive virts share W
    const int chunk = (virt >> 2) & 7;
    const int itile = virt >> 5;
    const int n     = chunk * 8 + (tid >> 5);
    const int d     = tid & 31;
    const int i0    = itile * TI_A;
    const int b0    = bg * 8;

    {   // stage x[b0..b0+7, i0..i0+7, :]: 1024 floats, 256 x float4, coalesced
        const int b = tid >> 5;             // 32 float4 per b (128 floats)
        const int r = (tid & 31) * 4;
        ((float4*)x_s)[tid] = *(const float4*)(x + (size_t)(b0 + b) * (IN_ * K_)
                                                 + (size_t)i0 * K_ + r);
    }
    __syncthreads();

    float s0[8];
    #pragma unroll
    for (int jb = 0; jb < 8; ++jb) s0[jb] = 0.f;

    const float* wbase = W + (((size_t)n * IN_ + i0) * D_ + d) * K_;

    #pragma unroll 1
    for (int ii = 0; ii < TI_A; ++ii) {
        const float4* wp = (const float4*)(wbase + (size_t)ii * (D_ * K_));
        const float4 w0 = wp[0], w1 = wp[1], w2 = wp[2], w3 = wp[3];
        unsigned short* up = uhat + (size_t)(i0 + ii) * (B_ * N_ * D_)
                                  + (size_t)b0 * (N_ * D_) + n * D_ + d;
        #pragma unroll
        for (int jb = 0; jb < 8; ++jb) {
            const float4 x0 = ((const float4*)&x_s[jb][ii][0])[0];  // broadcast
            const float4 x1 = ((const float4*)&x_s[jb][ii][0])[1];
            const float4 x2 = ((const float4*)&x_s[jb][ii][0])[2];
            const float4 x3 = ((const float4*)&x_s[jb][ii][0])[3];
            const float uh = w0.x*x0.x + w0.y*x0.y + w0.z*x0.z + w0.w*x0.w
                           + w1.x*x1.x + w1.y*x1.y + w1.z*x1.z + w1.w*x1.w
                           + w2.x*x2.x + w2.y*x2.y + w2.z*x2.z + w2.w*x2.w
                           + w3.x*x3.x + w3.y*x3.y + w3.z*x3.z + w3.w*x3.w;
            up[(size_t)jb * (N_ * D_)] = (unsigned short)rb(uh);
            s0[jb] += uh;
        }
    }

    float* myp = part + (size_t)itile * CELLS + ((size_t)b0 * N_ + n) * D_ + d;
    #pragma unroll
    for (int jb = 0; jb < 8; ++jb)
        myp[(size_t)jb * (N_ * D_)] = s0[jb] * (1.0f / 64.0f);
}

// -----------------------------------------------------------------------------
// routeB_kernel: one routing pass reading u_hat[i][b][n][d] (bf16, single
// touch, contiguous per (i,b)). Thread=(b-in-group, n): 256 thr = 4b x 64n;
// block=(i-tile of 16, b-group). logit = thread-local dot over d; softmax
// over n = one 64-lane butterfly; s_acc[32] in regs. R13/R14: ~58us/pass.
// -----------------------------------------------------------------------------
__global__ __launch_bounds__(256, 1)
void routeB_kernel(const unsigned short* __restrict__ uhat,
                   const float* __restrict__ os, float* __restrict__ part)
{
    const int tid  = threadIdx.x;
    const int jb   = tid >> 6;          // wave = batch-in-group
    const int n    = tid & 63;          // lane = n
    const int tile = blockIdx.x >> 3;
    const int bg   = blockIdx.x & 7;
    const int b    = bg * 4 + jb;
    const int i0   = tile * T_B;

    float s_acc[D_];
    #pragma unroll
    for (int d = 0; d < D_; ++d) s_acc[d] = 0.f;

    float osr[D_];
    {
        const float4* op = (const float4*)(os + ((size_t)b * N_ + n) * D_);
        #pragma unroll
        for (int d4 = 0; d4 < 8; ++d4) *(float4*)&osr[d4 * 4] = op[d4];
    }

    const unsigned short* up = uhat + ((size_t)i0 * B_ + b) * (N_ * D_) + n * D_;

    #pragma unroll 2
    for (int ii = 0; ii < T_B; ++ii) {
        const uint4 q0 = *(const uint4*)(up);
        const uint4 q1 = *(const uint4*)(up + 8);
        const uint4 q2 = *(const uint4*)(up + 16);
        const uint4 q3 = *(const uint4*)(up + 24);
        up += (size_t)B_ * N_ * D_;     // next i, same b

        float t = dot8(q0, osr) + dot8(q1, osr + 8)
                + dot8(q2, osr + 16) + dot8(q3, osr + 24);
        float mx = t;
        #pragma unroll
        for (int m = 1; m < 64; m <<= 1) mx = fmaxf(mx, __shfl_xor(mx, m, 64));
        const float e = exp2f((t - mx) * SM_SCALE);
        float sum = e;
        #pragma unroll
        for (int m = 1; m < 64; m <<= 1) sum += __shfl_xor(sum, m, 64);
        const float c = e / sum;
        acc8(s_acc, q0, c); acc8(s_acc + 8,  q1, c);
        acc8(s_acc + 16, q2, c); acc8(s_acc + 24, q3, c);
    }

    float4* myp = (float4*)(part + (size_t)tile * CELLS + ((size_t)b * N_ + n) * D_);
    #pragma unroll
    for (int d4 = 0; d4 < 8; ++d4) {
        float4 v;
        v.x = s_acc[d4*4 + 0]; v.y = s_acc[d4*4 + 1];
        v.z = s_acc[d4*4 + 2]; v.w = s_acc[d4*4 + 3];
        myp[d4] = v;
    }
}

// -----------------------------------------------------------------------------
// finishB_kernel: s = sum over ntiles tile-partials; out = squash(s);
// FINAL=false: os += out; FINAL=true: write d_out.
// -----------------------------------------------------------------------------
template<bool FINAL>
__global__ __launch_bounds__(256)
void finishB_kernel(const float* __restrict__ part, int ntiles,
                    float* __restrict__ os, float* __restrict__ out)
{
    const int gid = blockIdx.x * 256 + threadIdx.x;   // 0..65535 = b*2048+n*32+d
    float v = 0.f;
    for (int t = 0; t < ntiles; ++t) v += part[(size_t)t * CELLS + gid];
    float sq = v * v;
    #pragma unroll
    for (int m = 1; m < 32; m <<= 1) sq += __shfl_xor(sq, m, 64);  // sum over d
    const float scale = sqrtf(sq) / (1.0f + sq);
    const float o = v * scale;
    if (FINAL) out[gid] = o;
    else       os[gid] += o;
}

// =============================================================================
// ===== R8 fallback path -- used only if ws < ~320 MB =========================
// =============================================================================
#define BH    4
#define NBG   (B_/BH)
#define ITILE 8
#define NTILE (IN_/ITILE)
#define NBLK  (NTILE*NBG)
#define PCELLS ((size_t)BH*N_*D_)

__global__ __launch_bounds__(256)
void convert_kernel(const float4* __restrict__ W, uint4* __restrict__ W16)
{
    const size_t n8 = WELEMS / 8;
    const size_t stride = (size_t)gridDim.x * 256;
    for (size_t i = (size_t)blockIdx.x * 256 + threadIdx.x; i < n8; i += stride) {
        const float4 a = W[2 * i], b = W[2 * i + 1];
        uint4 o;
        o.x = rb(a.x) | (rb(a.y) << 16);
        o.y = rb(a.z) | (rb(a.w) << 16);
        o.z = rb(b.x) | (rb(b.y) << 16);
        o.w = rb(b.z) | (rb(b.w) << 16);
        W16[i] = o;
    }
}

template<bool FIRST>
__global__ __launch_bounds__(256, 1)
void route16_kernel(const float* __restrict__ x, const unsigned short* __restrict__ W16,
                    const float* __restrict__ os, float* __restrict__ part)
{
    __shared__ unsigned short uh_s[N_][D_][BH];
    __shared__ float logit_s[BH][N_];

    const int tid  = threadIdx.x;
    const int w    = tid >> 6;
    const int l    = tid & 63;
    const int d    = l & 31;
    const int hi   = l >> 5;
    const int slot = w * 2 + hi;

    const int virt = (blockIdx.x & 7) * (NBLK / 8) + (blockIdx.x >> 3);
    const int tile = virt / NBG;
    const int bg   = virt % NBG;
    const int b0   = bg * BH;
    const int i0   = tile * ITILE;

    float s_acc[8][BH];
    #pragma unroll
    for (int r = 0; r < 8; ++r)
        #pragma unroll
        for (int jb = 0; jb < BH; ++jb) s_acc[r][jb] = 0.f;

    const unsigned short* wb = W16 + (((size_t)slot * IN_ + i0) * D_ + d) * K_;

    for (int ii = 0; ii < ITILE; ++ii) {
        const float* xb = x + (size_t)b0 * (IN_ * K_) + (size_t)(i0 + ii) * K_;

        #pragma unroll
        for (int r = 0; r < 8; ++r) {
            const int n = r * 8 + slot;
            const unsigned short* wr = wb + (size_t)r * (8ull * IN_ * D_ * K_)
                                          + (size_t)ii * (D_ * K_);
            const uint4 plo = *(const uint4*)(wr);
            const uint4 phi = *(const uint4*)(wr + 8);
            float wf[16];
            wf[ 0]=blo(plo.x); wf[ 1]=bhi(plo.x); wf[ 2]=blo(plo.y); wf[ 3]=bhi(plo.y);
            wf[ 4]=blo(plo.z); wf[ 5]=bhi(plo.z); wf[ 6]=blo(plo.w); wf[ 7]=bhi(plo.w);
            wf[ 8]=blo(phi.x); wf[ 9]=bhi(phi.x); wf[10]=blo(phi.y); wf[11]=bhi(phi.y);
            wf[12]=blo(phi.z); wf[13]=bhi(phi.z); wf[14]=blo(phi.w); wf[15]=bhi(phi.w);

            float uh[BH];
            #pragma unroll
            for (int jb = 0; jb < BH; ++jb) {
                const float4 x0 = *(const float4*)(xb + (size_t)jb * (IN_ * K_) + 0);
                const float4 x1 = *(const float4*)(xb + (size_t)jb * (IN_ * K_) + 4);
                const float4 x2 = *(const float4*)(xb + (size_t)jb * (IN_ * K_) + 8);
                const float4 x3 = *(const float4*)(xb + (size_t)jb * (IN_ * K_) + 12);
                uh[jb] = wf[ 0]*x0.x + wf[ 1]*x0.y + wf[ 2]*x0.z + wf[ 3]*x0.w
                       + wf[ 4]*x1.x + wf[ 5]*x1.y + wf[ 6]*x1.z + wf[ 7]*x1.w
                       + wf[ 8]*x2.x + wf[ 9]*x2.y + wf[10]*x2.z + wf[11]*x2.w
                       + wf[12]*x3.x + wf[13]*x3.y + wf[14]*x3.z + wf[15]*x3.w;
            }

            if (FIRST) {
                #pragma unroll
                for (int jb = 0; jb < BH; ++jb) s_acc[r][jb] += uh[jb];
            } else {
                uint2 pk;
                pk.x = rb(uh[0]) | (rb(uh[1]) << 16);
                pk.y = rb(uh[2]) | (rb(uh[3]) << 16);
                *(uint2*)&uh_s[n][d][0] = pk;
                #pragma unroll
                for (int jb = 0; jb < BH; ++jb) {
                    float t = uh[jb] * os[((size_t)(b0 + jb) * N_ + n) * D_ + d];
                    #pragma unroll
                    for (int m = 1; m < 32; m <<= 1) t += __shfl_xor(t, m, 64);
                    if (d == 0) logit_s[jb][n] = t;
                }
            }
        }

        if (!FIRST) {
            __syncthreads();
            {
                const float v = logit_s[w][l];
                float mx = v;
                #pragma unroll
                for (int m = 1; m < 64; m <<= 1) mx = fmaxf(mx, __shfl_xor(mx, m, 64));
                const float e = exp2f((v - mx) * SM_SCALE);
                float sum = e;
                #pragma unroll
                for (int m = 1; m < 64; m <<= 1) sum += __shfl_xor(sum, m, 64);
                logit_s[w][l] = e / sum;
            }
            __syncthreads();
            #pragma unroll
            for (int r = 0; r < 8; ++r) {
                const int n = r * 8 + slot;
                const uint2 pk = *(const uint2*)&uh_s[n][d][0];
                s_acc[r][0] += logit_s[0][n] * blo(pk.x);
                s_acc[r][1] += logit_s[1][n] * bhi(pk.x);
                s_acc[r][2] += logit_s[2][n] * blo(pk.y);
                s_acc[r][3] += logit_s[3][n] * bhi(pk.y);
            }
            __syncthreads();
        }
    }

    const float scale = FIRST ? (1.0f / 64.0f) : 1.0f;
    float* myp = part + (size_t)virt * PCELLS;
    #pragma unroll
    for (int r = 0; r < 8; ++r) {
        const int n = r * 8 + slot;
        #pragma unroll
        for (int jb = 0; jb < BH; ++jb)
            myp[((size_t)jb * N_ + n) * D_ + d] = s_acc[r][jb] * scale;
    }
}

template<bool FINAL>
__global__ __launch_bounds__(256)
void finish_kernel(const float* __restrict__ part,
                   float* __restrict__ os, float* __restrict__ out)
{
    const int gid = blockIdx.x * 256 + threadIdx.x;
    const int b   = gid >> 11;
    const int rem = gid & 2047;
    const int bg = b >> 2, jb = b & 3;
    const float* p0 = part + (size_t)bg * PCELLS + (size_t)jb * (N_ * D_) + rem;
    float v = 0.f;
    for (int t = 0; t < NTILE; ++t) v += p0[(size_t)t * NBG * PCELLS];
    float sq = v * v;
    #pragma unroll
    for (int m = 1; m < 32; m <<= 1) sq += __shfl_xor(sq, m, 64);
    const float scale = sqrtf(sq) / (1.0f + sq);
    const float o = v * scale;
    if (FINAL) out[gid] = o;
    else       os[gid] += o;
}

extern "C" void kernel_launch(void* const* d_in, const int* in_sizes, int n_in,
                              void* d_out, int out_size, void* d_ws, size_t ws_size,
                              hipStream_t stream)
{
    const float* x = (const float*)d_in[0];
    const float* W = (const float*)d_in[1];
    float* out = (float*)d_out;

    const size_t partA_bytes = (size_t)NTILE_A * CELLS * 4;   // 64 MB (pass 0)
    const size_t need_new    = UH_BYTES + partA_bytes + CELLS * 4;

    if (ws_size >= need_new) {
        unsigned short* uhat = (unsigned short*)d_ws;
        float* part = (float*)((char*)d_ws + UH_BYTES);
        float* os   = part + (size_t)NTILE_A * CELLS;

        zero_kernel<<<CELLS / 1024, 256, 0, stream>>>((float4*)os);
        uhatD_kernel<<<NBLK_A, 256, 0, stream>>>(x, W, uhat, part);        // + pass 0
        finishB_kernel<false><<<CELLS / 256, 256, 0, stream>>>(part, NTILE_A, os, nullptr);
        routeB_kernel<<<NBLK_B, 256, 0, stream>>>(uhat, os, part);          // pass 1
        finishB_kernel<false><<<CELLS / 256, 256, 0, stream>>>(part, NTILE_B, os, nullptr);
        routeB_kernel<<<NBLK_B, 256, 0, stream>>>(uhat, os, part);          // pass 2
        finishB_kernel<true ><<<CELLS / 256, 256, 0, stream>>>(part, NTILE_B, nullptr, out);
        return;
    }

    // ---- R8 fallback (proven) ----
    const size_t w16_bytes = WELEMS * 2;
    unsigned short* W16 = (unsigned short*)d_ws;
    float* part = (float*)((char*)d_ws + w16_bytes);
    float* os   = part + (size_t)NBLK * PCELLS;

    zero_kernel<<<CELLS / 1024, 256, 0, stream>>>((float4*)os);
    convert_kernel<<<2048, 256, 0, stream>>>((const float4*)W, (uint4*)d_ws);

    for (int it = 0; it < 3; ++it) {
        if (it == 0) route16_kernel<true ><<<NBLK, 256, 0, stream>>>(x, W16, os, part);
        else         route16_kernel<false><<<NBLK, 256, 0, stream>>>(x, W16, os, part);
        if (it < 2)  finish_kernel<false><<<CELLS / 256, 256, 0, stream>>>(part, os, nullptr);
        else         finish_kernel<true ><<<CELLS / 256, 256, 0, stream>>>(part, nullptr, out);
    }
}

// Round 17
// 343.322 us; speedup vs baseline: 1.6495x; 1.3918x over previous
//
#include <hip/hip_runtime.h>

#define B_    32
#define N_    64
#define IN_   2048
#define D_    32
#define K_    16
#define CELLS  ((size_t)B_*N_*D_)      /* 65536 */
#define WELEMS ((size_t)N_*IN_*D_*K_)  /* 67108864 */
#define UH_ELEMS ((size_t)B_*IN_*N_*D_) /* 134217728 */
#define UH_BYTES (UH_ELEMS*2)          /* 256 MB */
#define T_B    16                       /* i's per routeB block */
#define NTILE_B (IN_/T_B)               /* 128 */
#define NBLK_B  (NTILE_B*8)             /* 1024 */

// softmax_e(v * INV_LOG2) == 2^((v-max) * (1/ln2)^2)
#define SM_SCALE 2.0813689810056077f

// ---- bf16 helpers (RNE) ----
__device__ __forceinline__ unsigned int rb(float f) {
    unsigned int u = __float_as_uint(f);
    return (u + 0x7fffu + ((u >> 16) & 1u)) >> 16;
}
__device__ __forceinline__ float blo(unsigned int u) { return __uint_as_float(u << 16); }
__device__ __forceinline__ float bhi(unsigned int u) { return __uint_as_float(u & 0xffff0000u); }

__device__ __forceinline__ float dot8(uint4 q, const float* o) {
    return blo(q.x)*o[0] + bhi(q.x)*o[1] + blo(q.y)*o[2] + bhi(q.y)*o[3]
         + blo(q.z)*o[4] + bhi(q.z)*o[5] + blo(q.w)*o[6] + bhi(q.w)*o[7];
}
__device__ __forceinline__ void acc8(float* s, uint4 q, float c) {
    s[0] += c*blo(q.x); s[1] += c*bhi(q.x); s[2] += c*blo(q.y); s[3] += c*bhi(q.y);
    s[4] += c*blo(q.z); s[5] += c*bhi(q.z); s[6] += c*blo(q.w); s[7] += c*bhi(q.w);
}

__global__ __launch_bounds__(256)
void zero_kernel(float4* __restrict__ os)
{
    os[blockIdx.x * 256 + threadIdx.x] = float4{0.f, 0.f, 0.f, 0.f};
}

// -----------------------------------------------------------------------------
// uhat2_kernel: u_hat[i][b][n][d] = sum_k W[n,i,d,k]*x[b,i,k], bf16 store.
// R17: thread = (n, d-PAIR) -- each thread computes d=2dp and 2dp+1.
// The 4 LDS x-reads per b are shared across both outputs (halves LDS reads)
// and the two bf16 results pack into ONE uint store (halves store count).
// FMA density ~80% vs R14's ~70%. W regs = 8 float4 = 32; total ~60 <= 64
// so full occupancy should hold (R5-R16 law: perf tracks occupancy).
// Block = (i, n-chunk of 16): 16n x 16dp = 256 thr; grid = IN_*4 = 8192.
// NO pass-0 fusion: R11/R15/R16 all proved fusion costs more (occupancy)
// than the saved pass gains.
// -----------------------------------------------------------------------------
__global__ __launch_bounds__(256, 1)
void uhat2_kernel(const float* __restrict__ x, const float* __restrict__ W,
                  unsigned short* __restrict__ uhat)
{
    __shared__ float x_s[B_][K_];   // 2 KB: x[b][k] for this block's i

    const int tid   = threadIdx.x;
    const int i     = blockIdx.x >> 2;
    const int chunk = blockIdx.x & 3;
    const int n     = chunk * 16 + (tid >> 4);
    const int dp    = tid & 15;          // d = 2*dp, 2*dp+1

    {   // stage x[:, i, :]: 512 floats, 256 threads x float2, coalesced
        const int idx = tid * 2;
        const int b = idx >> 4, k = idx & 15;
        *(float2*)&x_s[b][k] =
            *(const float2*)(x + (size_t)b * (IN_ * K_) + (size_t)i * K_ + k);
    }

    // two adjacent W rows (d=2dp, 2dp+1): 32 consecutive floats = 8 float4
    const float4* wp = (const float4*)(W + (((size_t)n * IN_ + i) * D_ + 2 * dp) * K_);
    const float4 wa0 = wp[0], wa1 = wp[1], wa2 = wp[2], wa3 = wp[3];
    const float4 wb0 = wp[4], wb1 = wp[5], wb2 = wp[6], wb3 = wp[7];

    __syncthreads();

    unsigned int* up = (unsigned int*)(uhat + (size_t)i * (B_ * N_ * D_)
                                            + (size_t)n * D_ + 2 * dp);

    #pragma unroll 8
    for (int b = 0; b < B_; ++b) {
        const float4 x0 = ((const float4*)x_s[b])[0];   // uniform -> broadcast
        const float4 x1 = ((const float4*)x_s[b])[1];
        const float4 x2 = ((const float4*)x_s[b])[2];
        const float4 x3 = ((const float4*)x_s[b])[3];
        const float uh0 = wa0.x*x0.x + wa0.y*x0.y + wa0.z*x0.z + wa0.w*x0.w
                        + wa1.x*x1.x + wa1.y*x1.y + wa1.z*x1.z + wa1.w*x1.w
                        + wa2.x*x2.x + wa2.y*x2.y + wa2.z*x2.z + wa2.w*x2.w
                        + wa3.x*x3.x + wa3.y*x3.y + wa3.z*x3.z + wa3.w*x3.w;
        const float uh1 = wb0.x*x0.x + wb0.y*x0.y + wb0.z*x0.z + wb0.w*x0.w
                        + wb1.x*x1.x + wb1.y*x1.y + wb1.z*x1.z + wb1.w*x1.w
                        + wb2.x*x2.x + wb2.y*x2.y + wb2.z*x2.z + wb2.w*x2.w
                        + wb3.x*x3.x + wb3.y*x3.y + wb3.z*x3.z + wb3.w*x3.w;
        up[(size_t)b * (N_ * D_ / 2)] = rb(uh0) | (rb(uh1) << 16);
    }
}

// -----------------------------------------------------------------------------
// routeB_kernel: one routing pass reading u_hat[i][b][n][d] (bf16, single
// touch, contiguous per (i,b)). Thread=(b-in-group, n): 256 thr = 4b x 64n;
// block=(i-tile of 16, b-group). logit = thread-local dot over d; softmax
// over n = one 64-lane butterfly; s_acc[32] in regs. PASS=false: iter 0,
// c = 1/64 uniform. R13/R14-measured ~58us/pass (88% of stream floor).
// -----------------------------------------------------------------------------
template<bool PASS>
__global__ __launch_bounds__(256, 1)
void routeB_kernel(const unsigned short* __restrict__ uhat,
                   const float* __restrict__ os, float* __restrict__ part)
{
    const int tid  = threadIdx.x;
    const int jb   = tid >> 6;          // wave = batch-in-group
    const int n    = tid & 63;          // lane = n
    const int tile = blockIdx.x >> 3;
    const int bg   = blockIdx.x & 7;
    const int b    = bg * 4 + jb;
    const int i0   = tile * T_B;

    float s_acc[D_];
    #pragma unroll
    for (int d = 0; d < D_; ++d) s_acc[d] = 0.f;

    float osr[D_];
    if (PASS) {
        const float4* op = (const float4*)(os + ((size_t)b * N_ + n) * D_);
        #pragma unroll
        for (int d4 = 0; d4 < 8; ++d4) *(float4*)&osr[d4 * 4] = op[d4];
    }

    const unsigned short* up = uhat + ((size_t)i0 * B_ + b) * (N_ * D_) + n * D_;

    #pragma unroll 2
    for (int ii = 0; ii < T_B; ++ii) {
        const uint4 q0 = *(const uint4*)(up);
        const uint4 q1 = *(const uint4*)(up + 8);
        const uint4 q2 = *(const uint4*)(up + 16);
        const uint4 q3 = *(const uint4*)(up + 24);
        up += (size_t)B_ * N_ * D_;     // next i, same b

        if (PASS) {
            float t = dot8(q0, osr) + dot8(q1, osr + 8)
                    + dot8(q2, osr + 16) + dot8(q3, osr + 24);
            float mx = t;
            #pragma unroll
            for (int m = 1; m < 64; m <<= 1) mx = fmaxf(mx, __shfl_xor(mx, m, 64));
            const float e = exp2f((t - mx) * SM_SCALE);
            float sum = e;
            #pragma unroll
            for (int m = 1; m < 64; m <<= 1) sum += __shfl_xor(sum, m, 64);
            const float c = e / sum;
            acc8(s_acc, q0, c); acc8(s_acc + 8,  q1, c);
            acc8(s_acc + 16, q2, c); acc8(s_acc + 24, q3, c);
        } else {
            acc8(s_acc, q0, 1.f); acc8(s_acc + 8,  q1, 1.f);
            acc8(s_acc + 16, q2, 1.f); acc8(s_acc + 24, q3, 1.f);
        }
    }

    const float scale = PASS ? 1.f : (1.f / 64.f);
    float4* myp = (float4*)(part + (size_t)tile * CELLS + ((size_t)b * N_ + n) * D_);
    #pragma unroll
    for (int d4 = 0; d4 < 8; ++d4) {
        float4 v;
        v.x = s_acc[d4*4 + 0] * scale; v.y = s_acc[d4*4 + 1] * scale;
        v.z = s_acc[d4*4 + 2] * scale; v.w = s_acc[d4*4 + 3] * scale;
        myp[d4] = v;
    }
}

// -----------------------------------------------------------------------------
// finishB_kernel: s = sum over NTILE_B tile-partials; out = squash(s);
// FINAL=false: os += out; FINAL=true: write d_out.
// -----------------------------------------------------------------------------
template<bool FINAL>
__global__ __launch_bounds__(256)
void finishB_kernel(const float* __restrict__ part,
                    float* __restrict__ os, float* __restrict__ out)
{
    const int gid = blockIdx.x * 256 + threadIdx.x;   // 0..65535 = b*2048+n*32+d
    float v = 0.f;
    for (int t = 0; t < NTILE_B; ++t) v += part[(size_t)t * CELLS + gid];
    float sq = v * v;
    #pragma unroll
    for (int m = 1; m < 32; m <<= 1) sq += __shfl_xor(sq, m, 64);  // sum over d
    const float scale = sqrtf(sq) / (1.0f + sq);
    const float o = v * scale;
    if (FINAL) out[gid] = o;
    else       os[gid] += o;
}

// =============================================================================
// ===== R8 fallback path -- used only if ws < ~320 MB =========================
// =============================================================================
#define BH    4
#define NBG   (B_/BH)
#define ITILE 8
#define NTILE (IN_/ITILE)
#define NBLK  (NTILE*NBG)
#define PCELLS ((size_t)BH*N_*D_)

__global__ __launch_bounds__(256)
void convert_kernel(const float4* __restrict__ W, uint4* __restrict__ W16)
{
    const size_t n8 = WELEMS / 8;
    const size_t stride = (size_t)gridDim.x * 256;
    for (size_t i = (size_t)blockIdx.x * 256 + threadIdx.x; i < n8; i += stride) {
        const float4 a = W[2 * i], b = W[2 * i + 1];
        uint4 o;
        o.x = rb(a.x) | (rb(a.y) << 16);
        o.y = rb(a.z) | (rb(a.w) << 16);
        o.z = rb(b.x) | (rb(b.y) << 16);
        o.w = rb(b.z) | (rb(b.w) << 16);
        W16[i] = o;
    }
}

template<bool FIRST>
__global__ __launch_bounds__(256, 1)
void route16_kernel(const float* __restrict__ x, const unsigned short* __restrict__ W16,
                    const float* __restrict__ os, float* __restrict__ part)
{
    __shared__ unsigned short uh_s[N_][D_][BH];
    __shared__ float logit_s[BH][N_];

    const int tid  = threadIdx.x;
    const int w    = tid >> 6;
    const int l    = tid & 63;
    const int d    = l & 31;
    const int hi   = l >> 5;
    const int slot = w * 2 + hi;

    const int virt = (blockIdx.x & 7) * (NBLK / 8) + (blockIdx.x >> 3);
    const int tile = virt / NBG;
    const int bg   = virt % NBG;
    const int b0   = bg * BH;
    const int i0   = tile * ITILE;

    float s_acc[8][BH];
    #pragma unroll
    for (int r = 0; r < 8; ++r)
        #pragma unroll
        for (int jb = 0; jb < BH; ++jb) s_acc[r][jb] = 0.f;

    const unsigned short* wb = W16 + (((size_t)slot * IN_ + i0) * D_ + d) * K_;

    for (int ii = 0; ii < ITILE; ++ii) {
        const float* xb = x + (size_t)b0 * (IN_ * K_) + (size_t)(i0 + ii) * K_;

        #pragma unroll
        for (int r = 0; r < 8; ++r) {
            const int n = r * 8 + slot;
            const unsigned short* wr = wb + (size_t)r * (8ull * IN_ * D_ * K_)
                                          + (size_t)ii * (D_ * K_);
            const uint4 plo = *(const uint4*)(wr);
            const uint4 phi = *(const uint4*)(wr + 8);
            float wf[16];
            wf[ 0]=blo(plo.x); wf[ 1]=bhi(plo.x); wf[ 2]=blo(plo.y); wf[ 3]=bhi(plo.y);
            wf[ 4]=blo(plo.z); wf[ 5]=bhi(plo.z); wf[ 6]=blo(plo.w); wf[ 7]=bhi(plo.w);
            wf[ 8]=blo(phi.x); wf[ 9]=bhi(phi.x); wf[10]=blo(phi.y); wf[11]=bhi(phi.y);
            wf[12]=blo(phi.z); wf[13]=bhi(phi.z); wf[14]=blo(phi.w); wf[15]=bhi(phi.w);

            float uh[BH];
            #pragma unroll
            for (int jb = 0; jb < BH; ++jb) {
                const float4 x0 = *(const float4*)(xb + (size_t)jb * (IN_ * K_) + 0);
                const float4 x1 = *(const float4*)(xb + (size_t)jb * (IN_ * K_) + 4);
                const float4 x2 = *(const float4*)(xb + (size_t)jb * (IN_ * K_) + 8);
                const float4 x3 = *(const float4*)(xb + (size_t)jb * (IN_ * K_) + 12);
                uh[jb] = wf[ 0]*x0.x + wf[ 1]*x0.y + wf[ 2]*x0.z + wf[ 3]*x0.w
                       + wf[ 4]*x1.x + wf[ 5]*x1.y + wf[ 6]*x1.z + wf[ 7]*x1.w
                       + wf[ 8]*x2.x + wf[ 9]*x2.y + wf[10]*x2.z + wf[11]*x2.w
                       + wf[12]*x3.x + wf[13]*x3.y + wf[14]*x3.z + wf[15]*x3.w;
            }

            if (FIRST) {
                #pragma unroll
                for (int jb = 0; jb < BH; ++jb) s_acc[r][jb] += uh[jb];
            } else {
                uint2 pk;
                pk.x = rb(uh[0]) | (rb(uh[1]) << 16);
                pk.y = rb(uh[2]) | (rb(uh[3]) << 16);
                *(uint2*)&uh_s[n][d][0] = pk;
                #pragma unroll
                for (int jb = 0; jb < BH; ++jb) {
                    float t = uh[jb] * os[((size_t)(b0 + jb) * N_ + n) * D_ + d];
                    #pragma unroll
                    for (int m = 1; m < 32; m <<= 1) t += __shfl_xor(t, m, 64);
                    if (d == 0) logit_s[jb][n] = t;
                }
            }
        }

        if (!FIRST) {
            __syncthreads();
            {
                const float v = logit_s[w][l];
                float mx = v;
                #pragma unroll
                for (int m = 1; m < 64; m <<= 1) mx = fmaxf(mx, __shfl_xor(mx, m, 64));
                const float e = exp2f((v - mx) * SM_SCALE);
                float sum = e;
                #pragma unroll
                for (int m = 1; m < 64; m <<= 1) sum += __shfl_xor(sum, m, 64);
                logit_s[w][l] = e / sum;
            }
            __syncthreads();
            #pragma unroll
            for (int r = 0; r < 8; ++r) {
                const int n = r * 8 + slot;
                const uint2 pk = *(const uint2*)&uh_s[n][d][0];
                s_acc[r][0] += logit_s[0][n] * blo(pk.x);
                s_acc[r][1] += logit_s[1][n] * bhi(pk.x);
                s_acc[r][2] += logit_s[2][n] * blo(pk.y);
                s_acc[r][3] += logit_s[3][n] * bhi(pk.y);
            }
            __syncthreads();
        }
    }

    const float scale = FIRST ? (1.0f / 64.0f) : 1.0f;
    float* myp = part + (size_t)virt * PCELLS;
    #pragma unroll
    for (int r = 0; r < 8; ++r) {
        const int n = r * 8 + slot;
        #pragma unroll
        for (int jb = 0; jb < BH; ++jb)
            myp[((size_t)jb * N_ + n) * D_ + d] = s_acc[r][jb] * scale;
    }
}

template<bool FINAL>
__global__ __launch_bounds__(256)
void finish_kernel(const float* __restrict__ part,
                   float* __restrict__ os, float* __restrict__ out)
{
    const int gid = blockIdx.x * 256 + threadIdx.x;
    const int b   = gid >> 11;
    const int rem = gid & 2047;
    const int bg = b >> 2, jb = b & 3;
    const float* p0 = part + (size_t)bg * PCELLS + (size_t)jb * (N_ * D_) + rem;
    float v = 0.f;
    for (int t = 0; t < NTILE; ++t) v += p0[(size_t)t * NBG * PCELLS];
    float sq = v * v;
    #pragma unroll
    for (int m = 1; m < 32; m <<= 1) sq += __shfl_xor(sq, m, 64);
    const float scale = sqrtf(sq) / (1.0f + sq);
    const float o = v * scale;
    if (FINAL) out[gid] = o;
    else       os[gid] += o;
}

extern "C" void kernel_launch(void* const* d_in, const int* in_sizes, int n_in,
                              void* d_out, int out_size, void* d_ws, size_t ws_size,
                              hipStream_t stream)
{
    const float* x = (const float*)d_in[0];
    const float* W = (const float*)d_in[1];
    float* out = (float*)d_out;

    const size_t partB_bytes = (size_t)NTILE_B * CELLS * 4;   // 32 MB
    const size_t need_new    = UH_BYTES + partB_bytes + CELLS * 4;

    if (ws_size >= need_new) {
        unsigned short* uhat = (unsigned short*)d_ws;
        float* part = (float*)((char*)d_ws + UH_BYTES);
        float* os   = part + (size_t)NTILE_B * CELLS;

        zero_kernel<<<CELLS / 1024, 256, 0, stream>>>((float4*)os);
        uhat2_kernel<<<IN_ * 4, 256, 0, stream>>>(x, W, uhat);

        routeB_kernel<false><<<NBLK_B, 256, 0, stream>>>(uhat, nullptr, part);
        finishB_kernel<false><<<CELLS / 256, 256, 0, stream>>>(part, os, nullptr);
        routeB_kernel<true ><<<NBLK_B, 256, 0, stream>>>(uhat, os, part);
        finishB_kernel<false><<<CELLS / 256, 256, 0, stream>>>(part, os, nullptr);
        routeB_kernel<true ><<<NBLK_B, 256, 0, stream>>>(uhat, os, part);
        finishB_kernel<true ><<<CELLS / 256, 256, 0, stream>>>(part, nullptr, out);
        return;
    }

    // ---- R8 fallback (proven) ----
    const size_t w16_bytes = WELEMS * 2;
    unsigned short* W16 = (unsigned short*)d_ws;
    float* part = (float*)((char*)d_ws + w16_bytes);
    float* os   = part + (size_t)NBLK * PCELLS;

    zero_kernel<<<CELLS / 1024, 256, 0, stream>>>((float4*)os);
    convert_kernel<<<2048, 256, 0, stream>>>((const float4*)W, (uint4*)d_ws);

    for (int it = 0; it < 3; ++it) {
        if (it == 0) route16_kernel<true ><<<NBLK, 256, 0, stream>>>(x, W16, os, part);
        else         route16_kernel<false><<<NBLK, 256, 0, stream>>>(x, W16, os, part);
        if (it < 2)  finish_kernel<false><<<CELLS / 256, 256, 0, stream>>>(part, os, nullptr);
        else         finish_kernel<true ><<<CELLS / 256, 256, 0, stream>>>(part, nullptr, out);
    }
}

// Round 18
// 330.263 us; speedup vs baseline: 1.7147x; 1.0395x over previous
//
#include <hip/hip_runtime.h>

#define B_    32
#define N_    64
#define IN_   2048
#define D_    32
#define K_    16
#define CELLS  ((size_t)B_*N_*D_)      /* 65536 */
#define WELEMS ((size_t)N_*IN_*D_*K_)  /* 67108864 */
#define UH_ELEMS ((size_t)B_*IN_*N_*D_) /* 134217728 */
#define UH_BYTES (UH_ELEMS*2)          /* 256 MB */
#define T_B    16                       /* i's per routeB block */
#define NTILE_B (IN_/T_B)               /* 128 */
#define NBLK_B  (NTILE_B*8)             /* 1024 */

// softmax_e(v * INV_LOG2) == 2^((v-max) * (1/ln2)^2)
#define SM_SCALE 2.0813689810056077f

// ---- bf16 helpers (RNE) ----
__device__ __forceinline__ unsigned int rb(float f) {
    unsigned int u = __float_as_uint(f);
    return (u + 0x7fffu + ((u >> 16) & 1u)) >> 16;
}
__device__ __forceinline__ float blo(unsigned int u) { return __uint_as_float(u << 16); }
__device__ __forceinline__ float bhi(unsigned int u) { return __uint_as_float(u & 0xffff0000u); }

__device__ __forceinline__ float dot8(uint4 q, const float* o) {
    return blo(q.x)*o[0] + bhi(q.x)*o[1] + blo(q.y)*o[2] + bhi(q.y)*o[3]
         + blo(q.z)*o[4] + bhi(q.z)*o[5] + blo(q.w)*o[6] + bhi(q.w)*o[7];
}
__device__ __forceinline__ void acc8(float* s, uint4 q, float c) {
    s[0] += c*blo(q.x); s[1] += c*bhi(q.x); s[2] += c*blo(q.y); s[3] += c*bhi(q.y);
    s[4] += c*blo(q.z); s[5] += c*bhi(q.z); s[6] += c*blo(q.w); s[7] += c*bhi(q.w);
}

// -----------------------------------------------------------------------------
// zero_kernel: os = 0 (in-graph memset replacement, R10/R11 lesson).
// -----------------------------------------------------------------------------
__global__ __launch_bounds__(256)
void zero_kernel(float4* __restrict__ os)
{
    os[blockIdx.x * 256 + threadIdx.x] = float4{0.f, 0.f, 0.f, 0.f};
}

// -----------------------------------------------------------------------------
// uhat_kernel (R14-proven, 131us): u_hat[i][b][n][d] = sum_k W[n,i,d,k]*x[b,i,k]
// bf16 store. Thread=(n,d), block=(i, n-chunk of 8). W read ONCE chip-wide,
// coalesced; x staged in LDS (R14 win: +23us over scalar s_loads), stores
// land in one contiguous 128KB i-plane. VGPR ~24, occ 86%.
// Experiments REJECTED by measurement: pass-0 fusion x3 (R11 VGPR cliff /
// R15 L2 churn / R16 VGPR cliff), d-pair threads (R17, +11us).
// -----------------------------------------------------------------------------
__global__ __launch_bounds__(256, 1)
void uhat_kernel(const float* __restrict__ x, const float* __restrict__ W,
                 unsigned short* __restrict__ uhat)
{
    __shared__ float x_s[B_][K_];   // 2 KB: x[b][k] for this block's i

    const int tid   = threadIdx.x;
    const int i     = blockIdx.x >> 3;
    const int chunk = blockIdx.x & 7;
    const int n     = chunk * 8 + (tid >> 5);
    const int d     = tid & 31;

    {   // stage x[:, i, :]: 512 floats, 256 threads x float2, coalesced
        const int idx = tid * 2;
        const int b = idx >> 4, k = idx & 15;
        *(float2*)&x_s[b][k] =
            *(const float2*)(x + (size_t)b * (IN_ * K_) + (size_t)i * K_ + k);
    }

    const float4* wp = (const float4*)(W + (((size_t)n * IN_ + i) * D_ + d) * K_);
    const float4 w0 = wp[0], w1 = wp[1], w2 = wp[2], w3 = wp[3];

    __syncthreads();

    unsigned short* up = uhat + (size_t)i * (B_ * N_ * D_) + n * D_ + d;  // [i][b][n][d]

    #pragma unroll 8
    for (int b = 0; b < B_; ++b) {
        const float4 x0 = ((const float4*)x_s[b])[0];   // uniform addr -> broadcast
        const float4 x1 = ((const float4*)x_s[b])[1];
        const float4 x2 = ((const float4*)x_s[b])[2];
        const float4 x3 = ((const float4*)x_s[b])[3];
        const float uh = w0.x*x0.x + w0.y*x0.y + w0.z*x0.z + w0.w*x0.w
                       + w1.x*x1.x + w1.y*x1.y + w1.z*x1.z + w1.w*x1.w
                       + w2.x*x2.x + w2.y*x2.y + w2.z*x2.z + w2.w*x2.w
                       + w3.x*x3.x + w3.y*x3.y + w3.z*x3.z + w3.w*x3.w;
        up[(size_t)b * (N_ * D_)] = (unsigned short)rb(uh);
    }
}

// -----------------------------------------------------------------------------
// routeB_kernel (R13/R14-proven, ~58us/pass): one routing pass over
// u_hat[i][b][n][d] (bf16, single-touch, contiguous per (i,b)).
// Thread=(b-in-group, n): 256 thr = 4b x 64n; block=(i-tile of 16, b-group).
// logit = thread-local dot over d (no shuffles); softmax over n = one 64-lane
// butterfly; s_acc[32] in regs. PASS=false: iteration 0, c = 1/64 uniform.
// -----------------------------------------------------------------------------
template<bool PASS>
__global__ __launch_bounds__(256, 1)
void routeB_kernel(const unsigned short* __restrict__ uhat,
                   const float* __restrict__ os, float* __restrict__ part)
{
    const int tid  = threadIdx.x;
    const int jb   = tid >> 6;          // wave = batch-in-group
    const int n    = tid & 63;          // lane = n
    const int tile = blockIdx.x >> 3;
    const int bg   = blockIdx.x & 7;
    const int b    = bg * 4 + jb;
    const int i0   = tile * T_B;

    float s_acc[D_];
    #pragma unroll
    for (int d = 0; d < D_; ++d) s_acc[d] = 0.f;

    float osr[D_];
    if (PASS) {
        const float4* op = (const float4*)(os + ((size_t)b * N_ + n) * D_);
        #pragma unroll
        for (int d4 = 0; d4 < 8; ++d4) *(float4*)&osr[d4 * 4] = op[d4];
    }

    const unsigned short* up = uhat + ((size_t)i0 * B_ + b) * (N_ * D_) + n * D_;

    #pragma unroll 2
    for (int ii = 0; ii < T_B; ++ii) {
        const uint4 q0 = *(const uint4*)(up);
        const uint4 q1 = *(const uint4*)(up + 8);
        const uint4 q2 = *(const uint4*)(up + 16);
        const uint4 q3 = *(const uint4*)(up + 24);
        up += (size_t)B_ * N_ * D_;     // next i, same b

        if (PASS) {
            float t = dot8(q0, osr) + dot8(q1, osr + 8)
                    + dot8(q2, osr + 16) + dot8(q3, osr + 24);
            float mx = t;
            #pragma unroll
            for (int m = 1; m < 64; m <<= 1) mx = fmaxf(mx, __shfl_xor(mx, m, 64));
            const float e = exp2f((t - mx) * SM_SCALE);
            float sum = e;
            #pragma unroll
            for (int m = 1; m < 64; m <<= 1) sum += __shfl_xor(sum, m, 64);
            const float c = e / sum;
            acc8(s_acc, q0, c); acc8(s_acc + 8,  q1, c);
            acc8(s_acc + 16, q2, c); acc8(s_acc + 24, q3, c);
        } else {
            acc8(s_acc, q0, 1.f); acc8(s_acc + 8,  q1, 1.f);
            acc8(s_acc + 16, q2, 1.f); acc8(s_acc + 24, q3, 1.f);
        }
    }

    const float scale = PASS ? 1.f : (1.f / 64.f);
    float4* myp = (float4*)(part + (size_t)tile * CELLS + ((size_t)b * N_ + n) * D_);
    #pragma unroll
    for (int d4 = 0; d4 < 8; ++d4) {
        float4 v;
        v.x = s_acc[d4*4 + 0] * scale; v.y = s_acc[d4*4 + 1] * scale;
        v.z = s_acc[d4*4 + 2] * scale; v.w = s_acc[d4*4 + 3] * scale;
        myp[d4] = v;
    }
}

// -----------------------------------------------------------------------------
// finishB_kernel: s = sum over NTILE_B tile-partials; out = squash(s);
// FINAL=false: os += out; FINAL=true: write d_out.
// -----------------------------------------------------------------------------
template<bool FINAL>
__global__ __launch_bounds__(256)
void finishB_kernel(const float* __restrict__ part,
                    float* __restrict__ os, float* __restrict__ out)
{
    const int gid = blockIdx.x * 256 + threadIdx.x;   // 0..65535 = b*2048+n*32+d
    float v = 0.f;
    for (int t = 0; t < NTILE_B; ++t) v += part[(size_t)t * CELLS + gid];
    float sq = v * v;
    #pragma unroll
    for (int m = 1; m < 32; m <<= 1) sq += __shfl_xor(sq, m, 64);  // sum over d
    const float scale = sqrtf(sq) / (1.0f + sq);
    const float o = v * scale;
    if (FINAL) out[gid] = o;
    else       os[gid] += o;
}

// =============================================================================
// ===== R8 fallback path -- used only if ws < ~320 MB =========================
// =============================================================================
#define BH    4
#define NBG   (B_/BH)
#define ITILE 8
#define NTILE (IN_/ITILE)
#define NBLK  (NTILE*NBG)
#define PCELLS ((size_t)BH*N_*D_)

__global__ __launch_bounds__(256)
void convert_kernel(const float4* __restrict__ W, uint4* __restrict__ W16)
{
    const size_t n8 = WELEMS / 8;
    const size_t stride = (size_t)gridDim.x * 256;
    for (size_t i = (size_t)blockIdx.x * 256 + threadIdx.x; i < n8; i += stride) {
        const float4 a = W[2 * i], b = W[2 * i + 1];
        uint4 o;
        o.x = rb(a.x) | (rb(a.y) << 16);
        o.y = rb(a.z) | (rb(a.w) << 16);
        o.z = rb(b.x) | (rb(b.y) << 16);
        o.w = rb(b.z) | (rb(b.w) << 16);
        W16[i] = o;
    }
}

template<bool FIRST>
__global__ __launch_bounds__(256, 1)
void route16_kernel(const float* __restrict__ x, const unsigned short* __restrict__ W16,
                    const float* __restrict__ os, float* __restrict__ part)
{
    __shared__ unsigned short uh_s[N_][D_][BH];
    __shared__ float logit_s[BH][N_];

    const int tid  = threadIdx.x;
    const int w    = tid >> 6;
    const int l    = tid & 63;
    const int d    = l & 31;
    const int hi   = l >> 5;
    const int slot = w * 2 + hi;

    const int virt = (blockIdx.x & 7) * (NBLK / 8) + (blockIdx.x >> 3);
    const int tile = virt / NBG;
    const int bg   = virt % NBG;
    const int b0   = bg * BH;
    const int i0   = tile * ITILE;

    float s_acc[8][BH];
    #pragma unroll
    for (int r = 0; r < 8; ++r)
        #pragma unroll
        for (int jb = 0; jb < BH; ++jb) s_acc[r][jb] = 0.f;

    const unsigned short* wb = W16 + (((size_t)slot * IN_ + i0) * D_ + d) * K_;

    for (int ii = 0; ii < ITILE; ++ii) {
        const float* xb = x + (size_t)b0 * (IN_ * K_) + (size_t)(i0 + ii) * K_;

        #pragma unroll
        for (int r = 0; r < 8; ++r) {
            const int n = r * 8 + slot;
            const unsigned short* wr = wb + (size_t)r * (8ull * IN_ * D_ * K_)
                                          + (size_t)ii * (D_ * K_);
            const uint4 plo = *(const uint4*)(wr);
            const uint4 phi = *(const uint4*)(wr + 8);
            float wf[16];
            wf[ 0]=blo(plo.x); wf[ 1]=bhi(plo.x); wf[ 2]=blo(plo.y); wf[ 3]=bhi(plo.y);
            wf[ 4]=blo(plo.z); wf[ 5]=bhi(plo.z); wf[ 6]=blo(plo.w); wf[ 7]=bhi(plo.w);
            wf[ 8]=blo(phi.x); wf[ 9]=bhi(phi.x); wf[10]=blo(phi.y); wf[11]=bhi(phi.y);
            wf[12]=blo(phi.z); wf[13]=bhi(phi.z); wf[14]=blo(phi.w); wf[15]=bhi(phi.w);

            float uh[BH];
            #pragma unroll
            for (int jb = 0; jb < BH; ++jb) {
                const float4 x0 = *(const float4*)(xb + (size_t)jb * (IN_ * K_) + 0);
                const float4 x1 = *(const float4*)(xb + (size_t)jb * (IN_ * K_) + 4);
                const float4 x2 = *(const float4*)(xb + (size_t)jb * (IN_ * K_) + 8);
                const float4 x3 = *(const float4*)(xb + (size_t)jb * (IN_ * K_) + 12);
                uh[jb] = wf[ 0]*x0.x + wf[ 1]*x0.y + wf[ 2]*x0.z + wf[ 3]*x0.w
                       + wf[ 4]*x1.x + wf[ 5]*x1.y + wf[ 6]*x1.z + wf[ 7]*x1.w
                       + wf[ 8]*x2.x + wf[ 9]*x2.y + wf[10]*x2.z + wf[11]*x2.w
                       + wf[12]*x3.x + wf[13]*x3.y + wf[14]*x3.z + wf[15]*x3.w;
            }

            if (FIRST) {
                #pragma unroll
                for (int jb = 0; jb < BH; ++jb) s_acc[r][jb] += uh[jb];
            } else {
                uint2 pk;
                pk.x = rb(uh[0]) | (rb(uh[1]) << 16);
                pk.y = rb(uh[2]) | (rb(uh[3]) << 16);
                *(uint2*)&uh_s[n][d][0] = pk;
                #pragma unroll
                for (int jb = 0; jb < BH; ++jb) {
                    float t = uh[jb] * os[((size_t)(b0 + jb) * N_ + n) * D_ + d];
                    #pragma unroll
                    for (int m = 1; m < 32; m <<= 1) t += __shfl_xor(t, m, 64);
                    if (d == 0) logit_s[jb][n] = t;
                }
            }
        }

        if (!FIRST) {
            __syncthreads();
            {
                const float v = logit_s[w][l];
                float mx = v;
                #pragma unroll
                for (int m = 1; m < 64; m <<= 1) mx = fmaxf(mx, __shfl_xor(mx, m, 64));
                const float e = exp2f((v - mx) * SM_SCALE);
                float sum = e;
                #pragma unroll
                for (int m = 1; m < 64; m <<= 1) sum += __shfl_xor(sum, m, 64);
                logit_s[w][l] = e / sum;
            }
            __syncthreads();
            #pragma unroll
            for (int r = 0; r < 8; ++r) {
                const int n = r * 8 + slot;
                const uint2 pk = *(const uint2*)&uh_s[n][d][0];
                s_acc[r][0] += logit_s[0][n] * blo(pk.x);
                s_acc[r][1] += logit_s[1][n] * bhi(pk.x);
                s_acc[r][2] += logit_s[2][n] * blo(pk.y);
                s_acc[r][3] += logit_s[3][n] * bhi(pk.y);
            }
            __syncthreads();
        }
    }

    const float scale = FIRST ? (1.0f / 64.0f) : 1.0f;
    float* myp = part + (size_t)virt * PCELLS;
    #pragma unroll
    for (int r = 0; r < 8; ++r) {
        const int n = r * 8 + slot;
        #pragma unroll
        for (int jb = 0; jb < BH; ++jb)
            myp[((size_t)jb * N_ + n) * D_ + d] = s_acc[r][jb] * scale;
    }
}

template<bool FINAL>
__global__ __launch_bounds__(256)
void finish_kernel(const float* __restrict__ part,
                   float* __restrict__ os, float* __restrict__ out)
{
    const int gid = blockIdx.x * 256 + threadIdx.x;
    const int b   = gid >> 11;
    const int rem = gid & 2047;
    const int bg = b >> 2, jb = b & 3;
    const float* p0 = part + (size_t)bg * PCELLS + (size_t)jb * (N_ * D_) + rem;
    float v = 0.f;
    for (int t = 0; t < NTILE; ++t) v += p0[(size_t)t * NBG * PCELLS];
    float sq = v * v;
    #pragma unroll
    for (int m = 1; m < 32; m <<= 1) sq += __shfl_xor(sq, m, 64);
    const float scale = sqrtf(sq) / (1.0f + sq);
    const float o = v * scale;
    if (FINAL) out[gid] = o;
    else       os[gid] += o;
}

extern "C" void kernel_launch(void* const* d_in, const int* in_sizes, int n_in,
                              void* d_out, int out_size, void* d_ws, size_t ws_size,
                              hipStream_t stream)
{
    const float* x = (const float*)d_in[0];
    const float* W = (const float*)d_in[1];
    float* out = (float*)d_out;

    const size_t partB_bytes = (size_t)NTILE_B * CELLS * 4;   // 32 MB
    const size_t need_new    = UH_BYTES + partB_bytes + CELLS * 4;

    if (ws_size >= need_new) {
        unsigned short* uhat = (unsigned short*)d_ws;
        float* part = (float*)((char*)d_ws + UH_BYTES);
        float* os   = part + (size_t)NTILE_B * CELLS;

        zero_kernel<<<CELLS / 1024, 256, 0, stream>>>((float4*)os);
        uhat_kernel<<<IN_ * 8, 256, 0, stream>>>(x, W, uhat);

        routeB_kernel<false><<<NBLK_B, 256, 0, stream>>>(uhat, nullptr, part);
        finishB_kernel<false><<<CELLS / 256, 256, 0, stream>>>(part, os, nullptr);
        routeB_kernel<true ><<<NBLK_B, 256, 0, stream>>>(uhat, os, part);
        finishB_kernel<false><<<CELLS / 256, 256, 0, stream>>>(part, os, nullptr);
        routeB_kernel<true ><<<NBLK_B, 256, 0, stream>>>(uhat, os, part);
        finishB_kernel<true ><<<CELLS / 256, 256, 0, stream>>>(part, nullptr, out);
        return;
    }

    // ---- R8 fallback (proven) ----
    const size_t w16_bytes = WELEMS * 2;
    unsigned short* W16 = (unsigned short*)d_ws;
    float* part = (float*)((char*)d_ws + w16_bytes);
    float* os   = part + (size_t)NBLK * PCELLS;

    zero_kernel<<<CELLS / 1024, 256, 0, stream>>>((float4*)os);
    convert_kernel<<<2048, 256, 0, stream>>>((const float4*)W, (uint4*)d_ws);

    for (int it = 0; it < 3; ++it) {
        if (it == 0) route16_kernel<true ><<<NBLK, 256, 0, stream>>>(x, W16, os, part);
        else         route16_kernel<false><<<NBLK, 256, 0, stream>>>(x, W16, os, part);
        if (it < 2)  finish_kernel<false><<<CELLS / 256, 256, 0, stream>>>(part, os, nullptr);
        else         finish_kernel<true ><<<CELLS / 256, 256, 0, stream>>>(part, nullptr, out);
    }
}